// Round 2
// baseline (364.191 us; speedup 1.0000x reference)
//
#include <hip/hip_runtime.h>
#include <cstdint>
#include <cstddef>

typedef _Float16 f16;
typedef f16 f16x2 __attribute__((ext_vector_type(2)));
typedef f16 f16x4 __attribute__((ext_vector_type(4)));
typedef f16 f16x8 __attribute__((ext_vector_type(8)));
typedef float f32x4 __attribute__((ext_vector_type(4)));

#define NEXP 8
#define BM 256
#define BN 256
#define BK 64

// async global->LDS, 16B per lane. LDS dest must be wave-uniform base + lane*16
// (staging index is tid*16 so this holds). Global source may be per-lane
// arbitrary (gathered rows / swizzled chunks are fine).
__device__ __forceinline__ void async_cp16(void* lds, const void* gsrc) {
  __builtin_amdgcn_global_load_lds(
      (const __attribute__((address_space(1))) void*)gsrc,
      (__attribute__((address_space(3))) void*)lds, 16, 0, 0);
}

// ---------------- K0: transpose gate weights gw[D,8] -> gwT[8,D] ----------------
__global__ __launch_bounds__(256) void k_gwT(const float* __restrict__ gw,
                                             float* __restrict__ gwT, int D) {
  int i = blockIdx.x * 256 + threadIdx.x;   // i < 8*D
  int e = i / D, d = i - e * D;
  gwT[i] = gw[d * NEXP + e];
}

// ---------------- K1: gating + x -> fp16 (single x pass, coalesced gwT) ------
__global__ __launch_bounds__(256) void k_gate(
    const float* __restrict__ x, const float* __restrict__ gwT,
    f16* __restrict__ xb, int* __restrict__ gate, float* __restrict__ scale,
    int* __restrict__ cnt, float* __restrict__ probsum, int D)
{
  __shared__ float ps[NEXP];
  __shared__ int pc[NEXP];
  int tid = threadIdx.x, lane = tid & 63, w = tid >> 6;
  if (tid < NEXP) { ps[tid] = 0.f; pc[tid] = 0; }
  __syncthreads();

  int t = blockIdx.x * 4 + w;
  const float* xr = x + (size_t)t * D;
  f16* xbr = xb + (size_t)t * D;

  float acc[NEXP] = {};
  for (int d0 = lane * 4; d0 < D; d0 += 256) {
    float4 v = *(const float4*)(xr + d0);
    f16x4 h; h[0] = (f16)v.x; h[1] = (f16)v.y; h[2] = (f16)v.z; h[3] = (f16)v.w;
    *(f16x4*)(xbr + d0) = h;
#pragma unroll
    for (int e = 0; e < NEXP; e++) {
      float4 g = *(const float4*)(gwT + (size_t)e * D + d0);
      acc[e] += v.x * g.x + v.y * g.y + v.z * g.z + v.w * g.w;
    }
  }
#pragma unroll
  for (int e = 0; e < NEXP; e++) {
    float v = acc[e];
    for (int o = 32; o > 0; o >>= 1) v += __shfl_xor(v, o);
    acc[e] = v;
  }
  if (lane == 0) {
    float m = acc[0]; int g = 0;
#pragma unroll
    for (int e = 1; e < NEXP; e++) if (acc[e] > m) { m = acc[e]; g = e; }
    float pr[NEXP]; float ssum = 0.f;
#pragma unroll
    for (int e = 0; e < NEXP; e++) { pr[e] = __expf(acc[e] - m); ssum += pr[e]; }
    float inv = 1.0f / ssum;
#pragma unroll
    for (int e = 0; e < NEXP; e++) atomicAdd(&ps[e], pr[e] * inv);
    atomicAdd(&pc[g], 1);
    gate[t] = g;
    scale[t] = pr[g] * inv;
  }
  __syncthreads();
  if (tid < NEXP) {
    atomicAdd(&probsum[tid], ps[tid]);
    atomicAdd(&cnt[tid], pc[tid]);
  }
}

// ---------------- K2: build Wfull^T in fp16 ----------------
__global__ __launch_bounds__(256) void k_wfull(
    const float* __restrict__ Wp, const float* __restrict__ rule,
    f16* __restrict__ wt, int Dp, int Op, int D, int O)
{
  int bid = blockIdx.x;
  int it = Dp >> 5, jt = Op >> 5;
  int itile = bid % it; bid /= it;
  int jtile = bid % jt; bid /= jt;
  int e = bid;
  int i0 = itile * 32, j0 = jtile * 32;

  __shared__ float Wt[4][32][33];
  int tid = threadIdx.x;
  for (int idx = tid; idx < 4096; idx += 256) {
    int p = idx >> 10, rem = idx & 1023, ii = rem >> 5, jj = rem & 31;
    Wt[p][ii][jj] = Wp[(size_t)((e * 4 + p) * Dp + i0 + ii) * Op + j0 + jj];
  }
  __syncthreads();

  int ii = (tid & 15) * 2, jjb = tid >> 4;
#pragma unroll
  for (int b = 0; b < 4; b++) {
    float s[4][4];
#pragma unroll
    for (int p = 0; p < 4; p++)
#pragma unroll
      for (int a = 0; a < 4; a++)
        s[p][a] = rule[((e * 4 + p) * 4 + a) * 4 + b];
#pragma unroll
    for (int a = 0; a < 4; a++) {
#pragma unroll
      for (int jp = 0; jp < 2; jp++) {
        int jj = jjb + jp * 16;
        float v0 = 0.f, v1 = 0.f;
#pragma unroll
        for (int p = 0; p < 4; p++) {
          v0 += s[p][a] * Wt[p][ii][jj];
          v1 += s[p][a] * Wt[p][ii + 1][jj];
        }
        size_t n = (size_t)b * Op + j0 + jj;
        size_t dd = (size_t)a * Dp + i0 + ii;
        f16x2 hv; hv[0] = (f16)v0; hv[1] = (f16)v1;
        *(f16x2*)(wt + ((size_t)e * O + n) * D + dd) = hv;
      }
    }
  }
}

// ---------------- K3: plan (scan, loss, descriptors) ----------------
__global__ __launch_bounds__(128) void k_plan(
    const int* __restrict__ cnt, const float* __restrict__ probsum,
    int* __restrict__ offs, int* __restrict__ ndesc,
    int2* __restrict__ desc, float* __restrict__ otail, int T)
{
  __shared__ int soffs[NEXP + 1];
  __shared__ int snd;
  __shared__ float sloss;
  __shared__ int2 sdesc[96];
  int tid = threadIdx.x;
  if (tid == 0) {
    int off = 0, nd = 0; float loss = 0.f;
    for (int e = 0; e < NEXP; e++) {
      soffs[e] = off;
      int c = cnt[e];
      loss += probsum[e] * (float)c;
      for (int m0 = 0; m0 < c; m0 += BM) { sdesc[nd] = make_int2(e, m0); nd++; }
      off += c;
    }
    soffs[NEXP] = off;
    snd = nd;
    sloss = loss;
  }
  __syncthreads();
  if (tid <= NEXP) offs[tid] = soffs[tid];
  if (tid == 9) *ndesc = snd;
  if (tid == 10) {
    float invT = 1.0f / (float)T;
    otail[0] = (float)NEXP * sloss * invT * invT;  // balance loss
  }
  if (tid >= 16 && tid < 16 + NEXP) otail[1 + tid - 16] = (float)cnt[tid - 16];
  for (int i = tid; i < snd; i += 128) desc[i] = sdesc[i];
}

// ---------------- K4: scatter tokens by expert ----------------
__global__ __launch_bounds__(256) void k_scatter(
    const int* __restrict__ gate, const int* __restrict__ offs,
    int* __restrict__ cursor, int* __restrict__ perm)
{
  int t = blockIdx.x * 256 + threadIdx.x;
  int g = gate[t];
  int lane = threadIdx.x & 63;
  int pos = 0;
#pragma unroll
  for (int e = 0; e < NEXP; e++) {
    unsigned long long mask = __ballot(g == e);
    if (mask == 0ull) continue;            // wave-uniform
    int leader = __ffsll((unsigned long long)mask) - 1;
    int base = 0;
    if (lane == leader) base = atomicAdd(&cursor[e], (int)__popcll(mask));
    base = __shfl(base, leader);
    if (g == e) {
      int below = (int)__popcll(mask & ((1ull << lane) - 1ull));
      pos = offs[e] + base + below;
    }
  }
  perm[pos] = t;
}

// ---------------- K5: gathered top-1 GEMM, faithful 8-phase schedule ---------
// 256x256 tile, 8 waves (2M x 4N, per-wave 128x64), BK=64, double-buffered LDS.
// Per K-tile: 4 phases keyed by (m-half, k-slice):
//   P0 (mh0,ks0): 4 A-reads + 4 B-reads | stage A(kt+1) rounds 0-1 -> buf^1
//   P1 (mh0,ks1): 4 A-reads + 4 B-reads | stage A(kt+1) rounds 2-3 -> buf^1
//   P2 (mh1,ks0): 4 A-reads  (B held)   | stage B(kt+2) rounds 0-1 -> buf
//   P3 (mh1,ks1): 4 A-reads  (B held)   | stage B(kt+2) rounds 2-3 -> buf
// each phase: reads; 2 staging loads; s_barrier; lgkmcnt(0); setprio(1);
// 16 MFMA; setprio(0); s_barrier. vmcnt(4) once per tile at P3's closing
// barrier (only B(kt+2)'s 4 loads stay in flight across the boundary — never
// drain to 0 mid-loop). Safety fences: B(buf) reads retire before P1's closing
// barrier, so P2/P3 may overwrite Bs[buf]; As[buf^1] was last read in tile
// kt-1's P3, so P0/P1 may overwrite it.
// Swizzle (unchanged, measured 0 conflicts): LDS slot s of row r holds global
// 16B chunk s ^ (r&7); readers use slot g ^ (lr&7).
__global__ __launch_bounds__(512, 2) void k_gemm(
    const f16* __restrict__ xb, const f16* __restrict__ wt,
    const float* __restrict__ bias, const int* __restrict__ perm,
    const int* __restrict__ cnt, const int* __restrict__ offs,
    const int* __restrict__ ndesc, const int2* __restrict__ desc,
    const float* __restrict__ scale, float* __restrict__ out, int D, int O)
{
  // grid: x = descriptor (XCD = desc%8 -> the 8 n0-blocks of one descriptor
  // are co-resident on one XCD and share the A panel in its L2), y = n0.
  if ((int)blockIdx.x >= *ndesc) return;
  int2 dsc = desc[blockIdx.x];
  int e = dsc.x, m0 = dsc.y;
  int ce = cnt[e];
  int seg = offs[e];
  int n0 = blockIdx.y * BN;

  __shared__ f16 As[2][BM * BK];   // 2 x 32KB
  __shared__ f16 Bs[2][BN * BK];   // 2 x 32KB
  __shared__ int tokS[BM];
  __shared__ float scS[BM];

  int tid = threadIdx.x;
  if (tid < BM) {
    int idx = m0 + tid; if (idx > ce - 1) idx = ce - 1;  // clamp partial tile
    int tok = perm[seg + idx];
    tokS[tid] = tok;
    scS[tid] = scale[tok];
  }
  __syncthreads();

  // staging: 512 threads x 16B = 8KB/round; 4 rounds per 32KB tensor-tile.
  // round rr: row = (tid>>3) + rr*64, slot c = tid&7, global chunk c^(row&7).
  int sr = tid >> 3, sc = tid & 7;
  uint32_t offA[4], offB[4];
#pragma unroll
  for (int rr = 0; rr < 4; rr++) {
    int row = sr + rr * 64;
    int gc = sc ^ (row & 7);
    offA[rr] = ((uint32_t)tokS[row] * (uint32_t)D + (uint32_t)(gc * 8)) * 2u;
    offB[rr] = ((uint32_t)(e * O + n0 + row) * (uint32_t)D + (uint32_t)(gc * 8)) * 2u;
  }

#define STAGE_A(kk, pb, r0)                                                   \
  do {                                                                        \
    _Pragma("unroll")                                                         \
    for (int rr = (r0); rr < (r0) + 2; rr++)                                  \
      async_cp16(&As[pb][rr * 4096 + tid * 8],                                \
                 (const char*)xb + offA[rr] + (uint32_t)(kk) * (BK * 2));     \
  } while (0)
#define STAGE_B(kk, pb, r0)                                                   \
  do {                                                                        \
    _Pragma("unroll")                                                         \
    for (int rr = (r0); rr < (r0) + 2; rr++)                                  \
      async_cp16(&Bs[pb][rr * 4096 + tid * 8],                                \
                 (const char*)wt + offB[rr] + (uint32_t)(kk) * (BK * 2));     \
  } while (0)

  int lane = tid & 63;
  int wid = tid >> 6;
  int wr = wid >> 2, wc = wid & 3;          // wave tile: rows wr*128, cols wc*64
  int lr = lane & 15, q = lane >> 4;
  int abase = wr * 8192 + lr * 64;          // + mh*4096 + mi*1024 + slot
  int bbase = wc * 4096 + lr * 64;          // + nh*2048 + ni*1024 + slot
  const int slotk[2] = { ((0 * 4 + q) ^ (lr & 7)) * 8,
                         ((1 * 4 + q) ^ (lr & 7)) * 8 };

#define READ_A(mh, ks)                                                        \
  _Pragma("unroll")                                                           \
  for (int mi = 0; mi < 4; mi++)                                              \
    af[mi] = *(const f16x8*)&Ab[abase + (mh) * 4096 + mi * 1024 + slotk[ks]];
#define READ_B(ks)                                                            \
  _Pragma("unroll")                                                           \
  for (int nh = 0; nh < 2; nh++)                                              \
    _Pragma("unroll")                                                         \
    for (int ni = 0; ni < 2; ni++)                                            \
      bf[ks][nh][ni] =                                                        \
          *(const f16x8*)&Bb[bbase + nh * 2048 + ni * 1024 + slotk[ks]];
#define MFMA16(mh, ks)                                                        \
  do {                                                                        \
    __builtin_amdgcn_s_setprio(1);                                            \
    _Pragma("unroll")                                                         \
    for (int mi = 0; mi < 4; mi++)                                            \
      _Pragma("unroll")                                                       \
      for (int nh = 0; nh < 2; nh++)                                          \
        _Pragma("unroll")                                                     \
        for (int ni = 0; ni < 2; ni++)                                        \
          acc[mh][mi][nh][ni] = __builtin_amdgcn_mfma_f32_16x16x32_f16(       \
              af[mi], bf[ks][nh][ni], acc[mh][mi][nh][ni], 0, 0, 0);          \
    __builtin_amdgcn_s_setprio(0);                                            \
  } while (0)
#define PBAR __builtin_amdgcn_s_barrier()
#define LGKM0 asm volatile("s_waitcnt lgkmcnt(0)" ::: "memory")

  f32x4 acc[2][4][2][2] = {};
  int nkt = D / BK;                          // 32

  // prologue: tiles 0 and 1 fully staged; allow tile-1's 8 loads in flight.
  STAGE_A(0, 0, 0); STAGE_A(0, 0, 2);
  STAGE_B(0, 0, 0); STAGE_B(0, 0, 2);
  STAGE_A(1, 1, 0); STAGE_A(1, 1, 2);
  STAGE_B(1, 1, 0); STAGE_B(1, 1, 2);
  asm volatile("s_waitcnt vmcnt(8)\n\ts_barrier" ::: "memory");

#pragma unroll 1
  for (int kt = 0; kt < nkt; ++kt) {
    int pb = kt & 1;
    const f16* Ab = &As[pb][0];
    const f16* Bb = &Bs[pb][0];
    f16x8 af[4], bf[2][2][2];
    bool stA = (kt >= 1) && (kt + 1 < nkt);   // A(kt+1) -> buf pb^1
    bool stB = (kt + 2 < nkt);                // B(kt+2) -> buf pb

    // ---- P0: (mh0, ks0) ----
    READ_A(0, 0); READ_B(0);
    if (stA) STAGE_A(kt + 1, pb ^ 1, 0);
    PBAR; LGKM0;
    MFMA16(0, 0);
    PBAR;

    // ---- P1: (mh0, ks1) ----
    READ_A(0, 1); READ_B(1);
    if (stA) STAGE_A(kt + 1, pb ^ 1, 2);
    PBAR; LGKM0;
    MFMA16(0, 1);
    PBAR;

    // ---- P2: (mh1, ks0) ----
    READ_A(1, 0);
    if (stB) STAGE_B(kt + 2, pb, 0);
    PBAR; LGKM0;
    MFMA16(1, 0);
    PBAR;

    // ---- P3: (mh1, ks1) ----
    READ_A(1, 1);
    if (stB) STAGE_B(kt + 2, pb, 2);
    PBAR; LGKM0;
    MFMA16(1, 1);
    if (stB) asm volatile("s_waitcnt vmcnt(4)" ::: "memory");
    else     asm volatile("s_waitcnt vmcnt(0)" ::: "memory");
    PBAR;
  }
#undef STAGE_A
#undef STAGE_B
#undef READ_A
#undef READ_B
#undef MFMA16
#undef PBAR
#undef LGKM0

  // epilogue: C/D layout col=lane&15, row=(lane>>4)*4+reg
  float bv[2][2];
#pragma unroll
  for (int nh = 0; nh < 2; nh++)
#pragma unroll
    for (int ni = 0; ni < 2; ni++)
      bv[nh][ni] = bias[(size_t)e * O + n0 + wc * 64 + nh * 32 + ni * 16 + lr];
#pragma unroll
  for (int mh = 0; mh < 2; mh++) {
#pragma unroll
    for (int mi = 0; mi < 4; mi++) {
#pragma unroll
      for (int rg = 0; rg < 4; rg++) {
        int rl = wr * 128 + mh * 64 + mi * 16 + q * 4 + rg;
        if (m0 + rl < ce) {
          float s = scS[rl];
          float* orow = out + (size_t)tokS[rl] * O + n0 + wc * 64;
#pragma unroll
          for (int nh = 0; nh < 2; nh++)
#pragma unroll
            for (int ni = 0; ni < 2; ni++)
              orow[nh * 32 + ni * 16 + lr] =
                  (acc[mh][mi][nh][ni][rg] + bv[nh][ni]) * s;
        }
      }
    }
  }
}

extern "C" void kernel_launch(void* const* d_in, const int* in_sizes, int n_in,
                              void* d_out, int out_size, void* d_ws, size_t ws_size,
                              hipStream_t stream)
{
  const float* x    = (const float*)d_in[0];   // [T, D]
  const float* gw   = (const float*)d_in[1];   // [D, 8]
  const float* rule = (const float*)d_in[2];   // [8, 4, 4, 4]
  const float* W    = (const float*)d_in[3];   // [8, 4, D/4, O/4]
  const float* bias = (const float*)d_in[4];   // [8, O]
  float* out = (float*)d_out;

  int D = in_sizes[1] / NEXP;
  int O = in_sizes[4] / NEXP;
  int T = in_sizes[0] / D;
  int Dp = D / 4, Op = O / 4;

  uint8_t* ws = (uint8_t*)d_ws;
  size_t off = 0;
  f16* xb = (f16*)(ws + off);  off += (size_t)T * D * 2;
  f16* wt = (f16*)(ws + off);  off += (size_t)NEXP * O * D * 2;
  int*   gate  = (int*)(ws + off);   off += (size_t)T * 4;
  float* scale = (float*)(ws + off); off += (size_t)T * 4;
  int*   perm  = (int*)(ws + off);   off += (size_t)T * 4;
  off = (off + 255) & ~(size_t)255;
  uint8_t* C = ws + off;
  int*   cnt     = (int*)(C + 0);
  float* probsum = (float*)(C + 32);
  int*   cursor  = (int*)(C + 64);
  int*   ndesc   = (int*)(C + 96);
  int*   offs    = (int*)(C + 128);
  int2*  desc    = (int2*)(C + 192);   // capacity to C+4096
  float* gwT     = (float*)(C + 4096); // [8, D] fp32

  // zero cnt/probsum/cursor/ndesc (ws is re-poisoned 0xAA before every call)
  hipMemsetAsync(C, 0, 128, stream);

  k_gwT<<<(NEXP * D) / 256, 256, 0, stream>>>(gw, gwT, D);
  k_gate<<<T / 4, 256, 0, stream>>>(x, gwT, xb, gate, scale, cnt, probsum, D);
  k_wfull<<<NEXP * (Op / 32) * (Dp / 32), 256, 0, stream>>>(W, rule, wt, Dp, Op, D, O);
  k_plan<<<1, 128, 0, stream>>>(cnt, probsum, offs, ndesc, desc, out + (size_t)T * O, T);
  k_scatter<<<T / 256, 256, 0, stream>>>(gate, offs, cursor, perm);

  int maxdesc = T / BM + NEXP;  // worst-case row-block descriptor count
  // grid transposed: x = descriptor, y = n0-block. linear%8 = x%8 (gridX=40
  // is a multiple of 8), so same-A-panel blocks land on the same XCD.
  k_gemm<<<dim3(maxdesc, O / BN), 512, 0, stream>>>(
      xb, wt, bias, perm, cnt, offs, ndesc, desc, scale, out, D, O);
}

// Round 3
// 344.296 us; speedup vs baseline: 1.0578x; 1.0578x over previous
//
#include <hip/hip_runtime.h>
#include <cstdint>
#include <cstddef>

typedef _Float16 f16;
typedef f16 f16x2 __attribute__((ext_vector_type(2)));
typedef f16 f16x4 __attribute__((ext_vector_type(4)));
typedef f16 f16x8 __attribute__((ext_vector_type(8)));
typedef float f32x4 __attribute__((ext_vector_type(4)));

#define NEXP 8
#define BM 128
#define BN 128
#define BK 32
#define NSTAGE 3

// async global->LDS, 16B per lane. LDS dest must be wave-uniform base + lane*16
// (staging index is tid*16 so this holds). Global source may be per-lane
// arbitrary (gathered rows / swizzled chunks are fine).
__device__ __forceinline__ void async_cp16(void* lds, const void* gsrc) {
  __builtin_amdgcn_global_load_lds(
      (const __attribute__((address_space(1))) void*)gsrc,
      (__attribute__((address_space(3))) void*)lds, 16, 0, 0);
}

// ---------------- K0: transpose gate weights gw[D,8] -> gwT[8,D] ----------------
__global__ __launch_bounds__(256) void k_gwT(const float* __restrict__ gw,
                                             float* __restrict__ gwT, int D) {
  int i = blockIdx.x * 256 + threadIdx.x;   // i < 8*D
  int e = i / D, d = i - e * D;
  gwT[i] = gw[d * NEXP + e];
}

// ---------------- K1: gating + x -> fp16 (single x pass, coalesced gwT) ------
// 256 threads = 4 waves, one token per wave. gwT (64KB) is L2-resident and
// every per-expert load is lane-contiguous (1 KB/wave-instr, 16 lines).
__global__ __launch_bounds__(256) void k_gate(
    const float* __restrict__ x, const float* __restrict__ gwT,
    f16* __restrict__ xb, int* __restrict__ gate, float* __restrict__ scale,
    int* __restrict__ cnt, float* __restrict__ probsum, int D)
{
  __shared__ float ps[NEXP];
  __shared__ int pc[NEXP];
  int tid = threadIdx.x, lane = tid & 63, w = tid >> 6;
  if (tid < NEXP) { ps[tid] = 0.f; pc[tid] = 0; }
  __syncthreads();

  int t = blockIdx.x * 4 + w;
  const float* xr = x + (size_t)t * D;
  f16* xbr = xb + (size_t)t * D;

  float acc[NEXP] = {};
  for (int d0 = lane * 4; d0 < D; d0 += 256) {
    float4 v = *(const float4*)(xr + d0);
    f16x4 h; h[0] = (f16)v.x; h[1] = (f16)v.y; h[2] = (f16)v.z; h[3] = (f16)v.w;
    *(f16x4*)(xbr + d0) = h;
#pragma unroll
    for (int e = 0; e < NEXP; e++) {
      float4 g = *(const float4*)(gwT + (size_t)e * D + d0);
      acc[e] += v.x * g.x + v.y * g.y + v.z * g.z + v.w * g.w;
    }
  }
#pragma unroll
  for (int e = 0; e < NEXP; e++) {
    float v = acc[e];
    for (int o = 32; o > 0; o >>= 1) v += __shfl_xor(v, o);
    acc[e] = v;
  }
  if (lane == 0) {
    float m = acc[0]; int g = 0;
#pragma unroll
    for (int e = 1; e < NEXP; e++) if (acc[e] > m) { m = acc[e]; g = e; }
    float pr[NEXP]; float ssum = 0.f;
#pragma unroll
    for (int e = 0; e < NEXP; e++) { pr[e] = __expf(acc[e] - m); ssum += pr[e]; }
    float inv = 1.0f / ssum;
#pragma unroll
    for (int e = 0; e < NEXP; e++) atomicAdd(&ps[e], pr[e] * inv);
    atomicAdd(&pc[g], 1);
    gate[t] = g;
    scale[t] = pr[g] * inv;
  }
  __syncthreads();
  if (tid < NEXP) {
    atomicAdd(&probsum[tid], ps[tid]);
    atomicAdd(&cnt[tid], pc[tid]);
  }
}

// ---------------- K2: build Wfull^T in fp16 ----------------
// wt[e][n][d] = sum_p rule[e,p,a,b] * W[e,p,i,j], d = a*Dp+i, n = b*Op+j.
// Thread -> (output row r = b*32+jj, d-half h). b = tid>>6 is wave-uniform so
// rule loads are scalar. Wt read once per (k,p) and reused across all 4 a
// (64 b32 reads/thread vs 256 before; lane pairs share the address -> max
// 2-way bank aliasing = free). Stores are f16x8 (16B), 8x fewer store
// instructions than the old f16x2 path, same cache-line footprint.
__global__ __launch_bounds__(256) void k_wfull(
    const float* __restrict__ Wp, const float* __restrict__ rule,
    f16* __restrict__ wt, int Dp, int Op, int D, int O)
{
  int bid = blockIdx.x;
  int it = Dp >> 5, jt = Op >> 5;
  int itile = bid % it; bid /= it;
  int jtile = bid % jt; bid /= jt;
  int e = bid;
  int i0 = itile * 32, j0 = jtile * 32;

  __shared__ float Wt[4][32][33];
  int tid = threadIdx.x;
  for (int idx = tid; idx < 4096; idx += 256) {
    int p = idx >> 10, rem = idx & 1023, ii = rem >> 5, jj = rem & 31;
    Wt[p][ii][jj] = Wp[(size_t)((e * 4 + p) * Dp + i0 + ii) * Op + j0 + jj];
  }
  __syncthreads();

  int r = tid >> 1;        // 0..127 output rows of this block
  int b = r >> 5;          // wave-uniform
  int jj = r & 31;
  int h = tid & 1;         // d-half: i = h*16 + k

  float s[4][4];
#pragma unroll
  for (int p = 0; p < 4; p++)
#pragma unroll
    for (int a = 0; a < 4; a++)
      s[p][a] = rule[((e * 4 + p) * 4 + a) * 4 + b];

  f16x8 outv[4][2];
#pragma unroll
  for (int k = 0; k < 16; k++) {
    int i = h * 16 + k;
    float w0 = Wt[0][i][jj], w1 = Wt[1][i][jj];
    float w2 = Wt[2][i][jj], w3 = Wt[3][i][jj];
#pragma unroll
    for (int a = 0; a < 4; a++) {
      float acc = s[0][a] * w0 + s[1][a] * w1 + s[2][a] * w2 + s[3][a] * w3;
      outv[a][k >> 3][k & 7] = (f16)acc;
    }
  }

  size_t rowbase = ((size_t)e * O + (size_t)b * Op + j0 + jj) * D + i0 + h * 16;
#pragma unroll
  for (int a = 0; a < 4; a++) {
    *(f16x8*)(wt + rowbase + (size_t)a * Dp)     = outv[a][0];
    *(f16x8*)(wt + rowbase + (size_t)a * Dp + 8) = outv[a][1];
  }
}

// ---------------- K3: plan (scan, loss, descriptors) ----------------
// Serial logic in LDS by thread 0 (16 global reads), then parallel writes
// (kills the ~80-deep serially-dependent global-write chain).
__global__ __launch_bounds__(128) void k_plan(
    const int* __restrict__ cnt, const float* __restrict__ probsum,
    int* __restrict__ offs, int* __restrict__ ndesc,
    int2* __restrict__ desc, float* __restrict__ otail, int T)
{
  __shared__ int soffs[NEXP + 1];
  __shared__ int snd;
  __shared__ float sloss;
  __shared__ int2 sdesc[96];
  int tid = threadIdx.x;
  if (tid == 0) {
    int off = 0, nd = 0; float loss = 0.f;
    for (int e = 0; e < NEXP; e++) {
      soffs[e] = off;
      int c = cnt[e];
      loss += probsum[e] * (float)c;
      for (int m0 = 0; m0 < c; m0 += BM) { sdesc[nd] = make_int2(e, m0); nd++; }
      off += c;
    }
    soffs[NEXP] = off;
    snd = nd;
    sloss = loss;
  }
  __syncthreads();
  if (tid <= NEXP) offs[tid] = soffs[tid];
  if (tid == 9) *ndesc = snd;
  if (tid == 10) {
    float invT = 1.0f / (float)T;
    otail[0] = (float)NEXP * sloss * invT * invT;  // balance loss
  }
  if (tid >= 16 && tid < 16 + NEXP) otail[1 + tid - 16] = (float)cnt[tid - 16];
  for (int i = tid; i < snd; i += 128) desc[i] = sdesc[i];
}

// ---------------- K4: scatter tokens by expert ----------------
__global__ __launch_bounds__(256) void k_scatter(
    const int* __restrict__ gate, const int* __restrict__ offs,
    int* __restrict__ cursor, int* __restrict__ perm)
{
  int t = blockIdx.x * 256 + threadIdx.x;
  int g = gate[t];
  int lane = threadIdx.x & 63;
  int pos = 0;
#pragma unroll
  for (int e = 0; e < NEXP; e++) {
    unsigned long long mask = __ballot(g == e);
    if (mask == 0ull) continue;            // wave-uniform
    int leader = __ffsll((unsigned long long)mask) - 1;
    int base = 0;
    if (lane == leader) base = atomicAdd(&cursor[e], (int)__popcll(mask));
    base = __shfl(base, leader);
    if (g == e) {
      int below = (int)__popcll(mask & ((1ull << lane) - 1ull));
      pos = offs[e] + base + below;
    }
  }
  perm[pos] = t;
}

// ---------------- K5: gathered top-1 GEMM ----------------
// 128x128 tile, BK=32, 3-stage LDS pipeline (prefetch distance 2), fine
// vmcnt barriers, XOR bank swizzle. Grid ncol-fastest for A/B cache reuse.
// (Round-0 proven kernel, 122 us; two 256x256 8-phase rewrites both
// regressed -> reverted.)
__global__ __launch_bounds__(256) void k_gemm(
    const f16* __restrict__ xb, const f16* __restrict__ wt,
    const float* __restrict__ bias, const int* __restrict__ perm,
    const int* __restrict__ cnt, const int* __restrict__ offs,
    const int* __restrict__ ndesc, const int2* __restrict__ desc,
    const float* __restrict__ scale, float* __restrict__ out, int D, int O)
{
  if ((int)blockIdx.y >= *ndesc) return;
  int2 dsc = desc[blockIdx.y];
  int e = dsc.x, m0 = dsc.y;
  int ce = cnt[e];
  int seg = offs[e];
  int n0 = blockIdx.x * BN;

  __shared__ f16 Al[NSTAGE][BM * BK];   // 3 x 8KB
  __shared__ f16 Bl[NSTAGE][BN * BK];   // 3 x 8KB
  __shared__ int tokS[BM];
  __shared__ float scS[BM];

  int tid = threadIdx.x;
  if (tid < BM) {
    int idx = m0 + tid; if (idx > ce - 1) idx = ce - 1;  // clamp partial tile
    int tok = perm[seg + idx];
    tokS[tid] = tok;
    scS[tid] = scale[tok];
  }
  __syncthreads();

  // staging: thread owns 16B chunk c of rows r and r+64; fetches global chunk
  // gc = c ^ ((r>>1)&3); MFMA reader un-swizzles with the same xor.
  int r = tid >> 2;   // 0..63
  int c = tid & 3;
  int gc = c ^ ((r >> 1) & 3);
  const f16* a1 = xb + (size_t)tokS[r] * D + gc * 8;
  const f16* a2 = xb + (size_t)tokS[r + 64] * D + gc * 8;
  const f16* b1 = wt + ((size_t)e * O + n0 + r) * D + gc * 8;
  const f16* b2 = wt + ((size_t)e * O + n0 + r + 64) * D + gc * 8;

  int lane = tid & 63;
  int w = tid >> 6;
  int wm = (w & 1) * 64, wn = (w >> 1) * 64;
  int lr = lane & 15, q = lane >> 4;
  int qs = q ^ ((lr >> 1) & 3);  // swizzled read chunk

  f32x4 acc[4][4] = {};
  int nk = D / BK;

#define STAGE(kk, p)                                             \
  do {                                                           \
    async_cp16(&Al[(p)][tid * 8], a1 + (kk) * BK);               \
    async_cp16(&Al[(p)][2048 + tid * 8], a2 + (kk) * BK);        \
    async_cp16(&Bl[(p)][tid * 8], b1 + (kk) * BK);               \
    async_cp16(&Bl[(p)][2048 + tid * 8], b2 + (kk) * BK);        \
  } while (0)

  STAGE(0, 0);
  STAGE(1, 1);
  STAGE(2, 2);

  int p = 0;
  for (int kk = 0; kk < nk; ++kk) {
    // tile kk must be complete; tiles kk+1, kk+2 (8 loads) may stay in flight
    int rem = nk - 1 - kk;
    if (rem >= 2)
      asm volatile("s_waitcnt vmcnt(8)\n\ts_barrier" ::: "memory");
    else if (rem == 1)
      asm volatile("s_waitcnt vmcnt(4)\n\ts_barrier" ::: "memory");
    else
      asm volatile("s_waitcnt vmcnt(0)\n\ts_barrier" ::: "memory");

    f16x8 af[4], bf[4];
#pragma unroll
    for (int mi = 0; mi < 4; mi++)
      af[mi] = *(const f16x8*)&Al[p][(wm + mi * 16 + lr) * BK + qs * 8];
#pragma unroll
    for (int ni = 0; ni < 4; ni++)
      bf[ni] = *(const f16x8*)&Bl[p][(wn + ni * 16 + lr) * BK + qs * 8];

    // all waves' ds_reads of buffer p done -> safe to restage it
    asm volatile("s_waitcnt lgkmcnt(0)\n\ts_barrier" ::: "memory");
    if (kk + NSTAGE < nk) STAGE(kk + NSTAGE, p);

#pragma unroll
    for (int mi = 0; mi < 4; mi++)
#pragma unroll
      for (int ni = 0; ni < 4; ni++)
        acc[mi][ni] = __builtin_amdgcn_mfma_f32_16x16x32_f16(
            af[mi], bf[ni], acc[mi][ni], 0, 0, 0);

    p++; if (p == NSTAGE) p = 0;
  }
#undef STAGE

  // epilogue: C/D layout col=lane&15, row=(lane>>4)*4+reg
  float bv[4];
#pragma unroll
  for (int ni = 0; ni < 4; ni++)
    bv[ni] = bias[(size_t)e * O + n0 + wn + ni * 16 + lr];
#pragma unroll
  for (int mi = 0; mi < 4; mi++) {
#pragma unroll
    for (int rg = 0; rg < 4; rg++) {
      int rl = wm + mi * 16 + q * 4 + rg;
      if (m0 + rl < ce) {
        float s = scS[rl];
        float* orow = out + (size_t)tokS[rl] * O + n0 + wn;
#pragma unroll
        for (int ni = 0; ni < 4; ni++)
          orow[ni * 16 + lr] = (acc[mi][ni][rg] + bv[ni]) * s;
      }
    }
  }
}

extern "C" void kernel_launch(void* const* d_in, const int* in_sizes, int n_in,
                              void* d_out, int out_size, void* d_ws, size_t ws_size,
                              hipStream_t stream)
{
  const float* x    = (const float*)d_in[0];   // [T, D]
  const float* gw   = (const float*)d_in[1];   // [D, 8]
  const float* rule = (const float*)d_in[2];   // [8, 4, 4, 4]
  const float* W    = (const float*)d_in[3];   // [8, 4, D/4, O/4]
  const float* bias = (const float*)d_in[4];   // [8, O]
  float* out = (float*)d_out;

  int D = in_sizes[1] / NEXP;
  int O = in_sizes[4] / NEXP;
  int T = in_sizes[0] / D;
  int Dp = D / 4, Op = O / 4;

  uint8_t* ws = (uint8_t*)d_ws;
  size_t off = 0;
  f16* xb = (f16*)(ws + off);  off += (size_t)T * D * 2;
  f16* wt = (f16*)(ws + off);  off += (size_t)NEXP * O * D * 2;
  int*   gate  = (int*)(ws + off);   off += (size_t)T * 4;
  float* scale = (float*)(ws + off); off += (size_t)T * 4;
  int*   perm  = (int*)(ws + off);   off += (size_t)T * 4;
  off = (off + 255) & ~(size_t)255;
  uint8_t* C = ws + off;
  int*   cnt     = (int*)(C + 0);
  float* probsum = (float*)(C + 32);
  int*   cursor  = (int*)(C + 64);
  int*   ndesc   = (int*)(C + 96);
  int*   offs    = (int*)(C + 128);
  int2*  desc    = (int2*)(C + 192);   // capacity to C+4096
  float* gwT     = (float*)(C + 4096); // [8, D] fp32

  // zero cnt/probsum/cursor/ndesc (ws is re-poisoned 0xAA before every call)
  hipMemsetAsync(C, 0, 128, stream);

  k_gwT<<<(NEXP * D) / 256, 256, 0, stream>>>(gw, gwT, D);
  k_gate<<<T / 4, 256, 0, stream>>>(x, gwT, xb, gate, scale, cnt, probsum, D);
  k_wfull<<<NEXP * (Op / 32) * (Dp / 32), 256, 0, stream>>>(W, rule, wt, Dp, Op, D, O);
  k_plan<<<1, 128, 0, stream>>>(cnt, probsum, offs, ndesc, desc, out + (size_t)T * O, T);
  k_scatter<<<T / 256, 256, 0, stream>>>(gate, offs, cursor, perm);

  int maxdesc = T / BM + NEXP;  // worst-case row-block descriptor count
  k_gemm<<<dim3(O / BN, maxdesc), 256, 0, stream>>>(
      xb, wt, bias, perm, cnt, offs, ndesc, desc, scale, out, D, O);
}

// Round 4
// 314.595 us; speedup vs baseline: 1.1576x; 1.0944x over previous
//
#include <hip/hip_runtime.h>
#include <cstdint>
#include <cstddef>

typedef _Float16 f16;
typedef f16 f16x2 __attribute__((ext_vector_type(2)));
typedef f16 f16x4 __attribute__((ext_vector_type(4)));
typedef f16 f16x8 __attribute__((ext_vector_type(8)));
typedef float f32x4 __attribute__((ext_vector_type(4)));

#define NEXP 8
#define BM 128
#define BN 128
#define BK 32
#define NSTAGE 3

// async global->LDS, 16B per lane. LDS dest must be wave-uniform base + lane*16
// (staging index is tid*16 so this holds). Global source may be per-lane
// arbitrary (gathered rows / swizzled chunks are fine).
__device__ __forceinline__ void async_cp16(void* lds, const void* gsrc) {
  __builtin_amdgcn_global_load_lds(
      (const __attribute__((address_space(1))) void*)gsrc,
      (__attribute__((address_space(3))) void*)lds, 16, 0, 0);
}

// ---------------- K1: gating + x -> fp16, LDS-staged gate weights ------------
// v2: the old version issued 8 gwT float4 loads per lane-iter through L1
// (64 KB of gwT re-read PER TOKEN => ~10.5 MB/CU through a ~307 GB/s/CU L1
// => ~34 us floor). Now: gw is staged into LDS once per block (two 32 KB
// half-passes, transposed [8][1028] with +4 pad -> conflict-free), and each
// WAVE processes 4 tokens so every gws float4 read feeds 4 tokens.
// Global traffic drops to the ideal: x read once (67 MB) + xb write (33.5 MB).
// gw[D][8] is read directly (contiguous) -> k_gwT kernel deleted.
// fp32 math and per-lane summation order identical to v1 (argmax-stable).
#define TPW 4
__global__ __launch_bounds__(256) void k_gate(
    const float* __restrict__ x, const float* __restrict__ gw,
    f16* __restrict__ xb, int* __restrict__ gate, float* __restrict__ scale,
    int* __restrict__ cnt, float* __restrict__ probsum, int D)
{
  __shared__ float gws[NEXP][1028];   // 1024 d-values per half-pass, +4 pad
  __shared__ float ps[NEXP];
  __shared__ int pc[NEXP];
  int tid = threadIdx.x, lane = tid & 63, w = tid >> 6;
  if (tid < NEXP) { ps[tid] = 0.f; pc[tid] = 0; }

  int t0 = (blockIdx.x * 4 + w) * TPW;     // wave's first token
  const float* xr = x + (size_t)t0 * D;
  f16* xbr = xb + (size_t)t0 * D;

  float acc[TPW][NEXP] = {};
  int nh = D >> 10;                        // half-passes of 1024 d each
  for (int half = 0; half < nh; half++) {
    // barrier: previous pass's reads (and ps/pc init) complete before restage
    __syncthreads();
    // stage gw[half*1024 + d][e] -> gws[e][d]; coalesced float2 global reads.
    // float f = 2*i: d = f>>3, e = f&7 (even). write banks (4e+d)%32: the
    // 4-lane same-d groups hit 8 distinct banks -> conflict-free.
    const float2* gsrc = (const float2*)(gw + (size_t)half * 1024 * NEXP);
    for (int i = tid; i < 4096; i += 256) {
      float2 v = gsrc[i];
      int f = i * 2;
      int d = f >> 3, e = f & 7;
      gws[e][d] = v.x;
      gws[e + 1][d] = v.y;
    }
    __syncthreads();

    int dh = half << 10;
#pragma unroll
    for (int it = 0; it < 4; it++) {
      int d0 = lane * 4 + it * 256;        // local d within this half
      float4 xv[TPW];
#pragma unroll
      for (int tp = 0; tp < TPW; tp++) {
        xv[tp] = *(const float4*)(xr + (size_t)tp * D + dh + d0);
        f16x4 h;
        h[0] = (f16)xv[tp].x; h[1] = (f16)xv[tp].y;
        h[2] = (f16)xv[tp].z; h[3] = (f16)xv[tp].w;
        *(f16x4*)(xbr + (size_t)tp * D + dh + d0) = h;
      }
#pragma unroll
      for (int e = 0; e < NEXP; e++) {
        float4 g = *(const float4*)&gws[e][d0];   // conflict-free, reused x4
#pragma unroll
        for (int tp = 0; tp < TPW; tp++)
          acc[tp][e] += xv[tp].x * g.x + xv[tp].y * g.y +
                        xv[tp].z * g.z + xv[tp].w * g.w;
      }
    }
  }

#pragma unroll
  for (int tp = 0; tp < TPW; tp++)
#pragma unroll
    for (int e = 0; e < NEXP; e++) {
      float v = acc[tp][e];
      for (int o = 32; o > 0; o >>= 1) v += __shfl_xor(v, o);
      acc[tp][e] = v;
    }

  if (lane == 0) {
#pragma unroll
    for (int tp = 0; tp < TPW; tp++) {
      float m = acc[tp][0]; int g = 0;
#pragma unroll
      for (int e = 1; e < NEXP; e++) if (acc[tp][e] > m) { m = acc[tp][e]; g = e; }
      float pr[NEXP]; float ssum = 0.f;
#pragma unroll
      for (int e = 0; e < NEXP; e++) { pr[e] = __expf(acc[tp][e] - m); ssum += pr[e]; }
      float inv = 1.0f / ssum;
#pragma unroll
      for (int e = 0; e < NEXP; e++) atomicAdd(&ps[e], pr[e] * inv);
      atomicAdd(&pc[g], 1);
      gate[t0 + tp] = g;
      scale[t0 + tp] = pr[g] * inv;
    }
  }
  __syncthreads();
  if (tid < NEXP) {
    atomicAdd(&probsum[tid], ps[tid]);
    atomicAdd(&cnt[tid], pc[tid]);
  }
}

// ---------------- K2: build Wfull^T in fp16 ----------------
// wt[e][n][d] = sum_p rule[e,p,a,b] * W[e,p,i,j], d = a*Dp+i, n = b*Op+j.
// Thread -> (output row r = b*32+jj, d-half h). b = tid>>6 is wave-uniform so
// rule loads are scalar. Wt read once per (k,p) and reused across all 4 a;
// f16x8 (16B) stores.
__global__ __launch_bounds__(256) void k_wfull(
    const float* __restrict__ Wp, const float* __restrict__ rule,
    f16* __restrict__ wt, int Dp, int Op, int D, int O)
{
  int bid = blockIdx.x;
  int it = Dp >> 5, jt = Op >> 5;
  int itile = bid % it; bid /= it;
  int jtile = bid % jt; bid /= jt;
  int e = bid;
  int i0 = itile * 32, j0 = jtile * 32;

  __shared__ float Wt[4][32][33];
  int tid = threadIdx.x;
  for (int idx = tid; idx < 4096; idx += 256) {
    int p = idx >> 10, rem = idx & 1023, ii = rem >> 5, jj = rem & 31;
    Wt[p][ii][jj] = Wp[(size_t)((e * 4 + p) * Dp + i0 + ii) * Op + j0 + jj];
  }
  __syncthreads();

  int r = tid >> 1;        // 0..127 output rows of this block
  int b = r >> 5;          // wave-uniform
  int jj = r & 31;
  int h = tid & 1;         // d-half: i = h*16 + k

  float s[4][4];
#pragma unroll
  for (int p = 0; p < 4; p++)
#pragma unroll
    for (int a = 0; a < 4; a++)
      s[p][a] = rule[((e * 4 + p) * 4 + a) * 4 + b];

  f16x8 outv[4][2];
#pragma unroll
  for (int k = 0; k < 16; k++) {
    int i = h * 16 + k;
    float w0 = Wt[0][i][jj], w1 = Wt[1][i][jj];
    float w2 = Wt[2][i][jj], w3 = Wt[3][i][jj];
#pragma unroll
    for (int a = 0; a < 4; a++) {
      float acc = s[0][a] * w0 + s[1][a] * w1 + s[2][a] * w2 + s[3][a] * w3;
      outv[a][k >> 3][k & 7] = (f16)acc;
    }
  }

  size_t rowbase = ((size_t)e * O + (size_t)b * Op + j0 + jj) * D + i0 + h * 16;
#pragma unroll
  for (int a = 0; a < 4; a++) {
    *(f16x8*)(wt + rowbase + (size_t)a * Dp)     = outv[a][0];
    *(f16x8*)(wt + rowbase + (size_t)a * Dp + 8) = outv[a][1];
  }
}

// ---------------- K3: plan (scan, loss, descriptors) ----------------
__global__ __launch_bounds__(128) void k_plan(
    const int* __restrict__ cnt, const float* __restrict__ probsum,
    int* __restrict__ offs, int* __restrict__ ndesc,
    int2* __restrict__ desc, float* __restrict__ otail, int T)
{
  __shared__ int soffs[NEXP + 1];
  __shared__ int snd;
  __shared__ float sloss;
  __shared__ int2 sdesc[96];
  int tid = threadIdx.x;
  if (tid == 0) {
    int off = 0, nd = 0; float loss = 0.f;
    for (int e = 0; e < NEXP; e++) {
      soffs[e] = off;
      int c = cnt[e];
      loss += probsum[e] * (float)c;
      for (int m0 = 0; m0 < c; m0 += BM) { sdesc[nd] = make_int2(e, m0); nd++; }
      off += c;
    }
    soffs[NEXP] = off;
    snd = nd;
    sloss = loss;
  }
  __syncthreads();
  if (tid <= NEXP) offs[tid] = soffs[tid];
  if (tid == 9) *ndesc = snd;
  if (tid == 10) {
    float invT = 1.0f / (float)T;
    otail[0] = (float)NEXP * sloss * invT * invT;  // balance loss
  }
  if (tid >= 16 && tid < 16 + NEXP) otail[1 + tid - 16] = (float)cnt[tid - 16];
  for (int i = tid; i < snd; i += 128) desc[i] = sdesc[i];
}

// ---------------- K4: scatter tokens by expert ----------------
__global__ __launch_bounds__(256) void k_scatter(
    const int* __restrict__ gate, const int* __restrict__ offs,
    int* __restrict__ cursor, int* __restrict__ perm)
{
  int t = blockIdx.x * 256 + threadIdx.x;
  int g = gate[t];
  int lane = threadIdx.x & 63;
  int pos = 0;
#pragma unroll
  for (int e = 0; e < NEXP; e++) {
    unsigned long long mask = __ballot(g == e);
    if (mask == 0ull) continue;            // wave-uniform
    int leader = __ffsll((unsigned long long)mask) - 1;
    int base = 0;
    if (lane == leader) base = atomicAdd(&cursor[e], (int)__popcll(mask));
    base = __shfl(base, leader);
    if (g == e) {
      int below = (int)__popcll(mask & ((1ull << lane) - 1ull));
      pos = offs[e] + base + below;
    }
  }
  perm[pos] = t;
}

// ---------------- K5: gathered top-1 GEMM ----------------
// 128x128 tile, BK=32, 3-stage LDS pipeline (prefetch distance 2), fine
// vmcnt barriers, XOR bank swizzle. Grid ncol-fastest for A/B cache reuse.
// (Round-0 proven kernel, 122 us; two 256x256 8-phase rewrites both
// regressed -> frozen.)
__global__ __launch_bounds__(256) void k_gemm(
    const f16* __restrict__ xb, const f16* __restrict__ wt,
    const float* __restrict__ bias, const int* __restrict__ perm,
    const int* __restrict__ cnt, const int* __restrict__ offs,
    const int* __restrict__ ndesc, const int2* __restrict__ desc,
    const float* __restrict__ scale, float* __restrict__ out, int D, int O)
{
  if ((int)blockIdx.y >= *ndesc) return;
  int2 dsc = desc[blockIdx.y];
  int e = dsc.x, m0 = dsc.y;
  int ce = cnt[e];
  int seg = offs[e];
  int n0 = blockIdx.x * BN;

  __shared__ f16 Al[NSTAGE][BM * BK];   // 3 x 8KB
  __shared__ f16 Bl[NSTAGE][BN * BK];   // 3 x 8KB
  __shared__ int tokS[BM];
  __shared__ float scS[BM];

  int tid = threadIdx.x;
  if (tid < BM) {
    int idx = m0 + tid; if (idx > ce - 1) idx = ce - 1;  // clamp partial tile
    int tok = perm[seg + idx];
    tokS[tid] = tok;
    scS[tid] = scale[tok];
  }
  __syncthreads();

  // staging: thread owns 16B chunk c of rows r and r+64; fetches global chunk
  // gc = c ^ ((r>>1)&3); MFMA reader un-swizzles with the same xor.
  int r = tid >> 2;   // 0..63
  int c = tid & 3;
  int gc = c ^ ((r >> 1) & 3);
  const f16* a1 = xb + (size_t)tokS[r] * D + gc * 8;
  const f16* a2 = xb + (size_t)tokS[r + 64] * D + gc * 8;
  const f16* b1 = wt + ((size_t)e * O + n0 + r) * D + gc * 8;
  const f16* b2 = wt + ((size_t)e * O + n0 + r + 64) * D + gc * 8;

  int lane = tid & 63;
  int w = tid >> 6;
  int wm = (w & 1) * 64, wn = (w >> 1) * 64;
  int lr = lane & 15, q = lane >> 4;
  int qs = q ^ ((lr >> 1) & 3);  // swizzled read chunk

  f32x4 acc[4][4] = {};
  int nk = D / BK;

#define STAGE(kk, p)                                             \
  do {                                                           \
    async_cp16(&Al[(p)][tid * 8], a1 + (kk) * BK);               \
    async_cp16(&Al[(p)][2048 + tid * 8], a2 + (kk) * BK);        \
    async_cp16(&Bl[(p)][tid * 8], b1 + (kk) * BK);               \
    async_cp16(&Bl[(p)][2048 + tid * 8], b2 + (kk) * BK);        \
  } while (0)

  STAGE(0, 0);
  STAGE(1, 1);
  STAGE(2, 2);

  int p = 0;
  for (int kk = 0; kk < nk; ++kk) {
    // tile kk must be complete; tiles kk+1, kk+2 (8 loads) may stay in flight
    int rem = nk - 1 - kk;
    if (rem >= 2)
      asm volatile("s_waitcnt vmcnt(8)\n\ts_barrier" ::: "memory");
    else if (rem == 1)
      asm volatile("s_waitcnt vmcnt(4)\n\ts_barrier" ::: "memory");
    else
      asm volatile("s_waitcnt vmcnt(0)\n\ts_barrier" ::: "memory");

    f16x8 af[4], bf[4];
#pragma unroll
    for (int mi = 0; mi < 4; mi++)
      af[mi] = *(const f16x8*)&Al[p][(wm + mi * 16 + lr) * BK + qs * 8];
#pragma unroll
    for (int ni = 0; ni < 4; ni++)
      bf[ni] = *(const f16x8*)&Bl[p][(wn + ni * 16 + lr) * BK + qs * 8];

    // all waves' ds_reads of buffer p done -> safe to restage it
    asm volatile("s_waitcnt lgkmcnt(0)\n\ts_barrier" ::: "memory");
    if (kk + NSTAGE < nk) STAGE(kk + NSTAGE, p);

#pragma unroll
    for (int mi = 0; mi < 4; mi++)
#pragma unroll
      for (int ni = 0; ni < 4; ni++)
        acc[mi][ni] = __builtin_amdgcn_mfma_f32_16x16x32_f16(
            af[mi], bf[ni], acc[mi][ni], 0, 0, 0);

    p++; if (p == NSTAGE) p = 0;
  }
#undef STAGE

  // epilogue: C/D layout col=lane&15, row=(lane>>4)*4+reg
  float bv[4];
#pragma unroll
  for (int ni = 0; ni < 4; ni++)
    bv[ni] = bias[(size_t)e * O + n0 + wn + ni * 16 + lr];
#pragma unroll
  for (int mi = 0; mi < 4; mi++) {
#pragma unroll
    for (int rg = 0; rg < 4; rg++) {
      int rl = wm + mi * 16 + q * 4 + rg;
      if (m0 + rl < ce) {
        float s = scS[rl];
        float* orow = out + (size_t)tokS[rl] * O + n0 + wn;
#pragma unroll
        for (int ni = 0; ni < 4; ni++)
          orow[ni * 16 + lr] = (acc[mi][ni][rg] + bv[ni]) * s;
      }
    }
  }
}

extern "C" void kernel_launch(void* const* d_in, const int* in_sizes, int n_in,
                              void* d_out, int out_size, void* d_ws, size_t ws_size,
                              hipStream_t stream)
{
  const float* x    = (const float*)d_in[0];   // [T, D]
  const float* gw   = (const float*)d_in[1];   // [D, 8]
  const float* rule = (const float*)d_in[2];   // [8, 4, 4, 4]
  const float* W    = (const float*)d_in[3];   // [8, 4, D/4, O/4]
  const float* bias = (const float*)d_in[4];   // [8, O]
  float* out = (float*)d_out;

  int D = in_sizes[1] / NEXP;
  int O = in_sizes[4] / NEXP;
  int T = in_sizes[0] / D;
  int Dp = D / 4, Op = O / 4;

  uint8_t* ws = (uint8_t*)d_ws;
  size_t off = 0;
  f16* xb = (f16*)(ws + off);  off += (size_t)T * D * 2;
  f16* wt = (f16*)(ws + off);  off += (size_t)NEXP * O * D * 2;
  int*   gate  = (int*)(ws + off);   off += (size_t)T * 4;
  float* scale = (float*)(ws + off); off += (size_t)T * 4;
  int*   perm  = (int*)(ws + off);   off += (size_t)T * 4;
  off = (off + 255) & ~(size_t)255;
  uint8_t* C = ws + off;
  int*   cnt     = (int*)(C + 0);
  float* probsum = (float*)(C + 32);
  int*   cursor  = (int*)(C + 64);
  int*   ndesc   = (int*)(C + 96);
  int*   offs    = (int*)(C + 128);
  int2*  desc    = (int2*)(C + 192);   // capacity to C+4096

  // zero cnt/probsum/cursor/ndesc (ws is re-poisoned 0xAA before every call)
  hipMemsetAsync(C, 0, 128, stream);

  // k_gwT deleted: k_gate reads gw[D][8] directly (contiguous) and
  // transposes into LDS.
  k_gate<<<T / (4 * TPW), 256, 0, stream>>>(x, gw, xb, gate, scale, cnt, probsum, D);
  k_wfull<<<NEXP * (Op / 32) * (Dp / 32), 256, 0, stream>>>(W, rule, wt, Dp, Op, D, O);
  k_plan<<<1, 128, 0, stream>>>(cnt, probsum, offs, ndesc, desc, out + (size_t)T * O, T);
  k_scatter<<<T / 256, 256, 0, stream>>>(gate, offs, cursor, perm);

  int maxdesc = T / BM + NEXP;  // worst-case row-block descriptor count
  k_gemm<<<dim3(O / BN, maxdesc), 256, 0, stream>>>(
      xb, wt, bias, perm, cnt, offs, ndesc, desc, scale, out, D, O);
}